// Round 15
// baseline (337.731 us; speedup 1.0000x reference)
//
#include <hip/hip_runtime.h>
#include <hip/hip_bf16.h>

// 2-layer GCN + mean pool. N=100000, E=1600000, G=128. dims 3 -> 64 -> 128.
//   h1  = relu( (A_hat x) @ W1 + b1 )        -- aggregate 3-dim x, then tiny GEMM
//   out = (mean_g (A_hat h1)) @ W2 + b2      -- aggregate 64-dim h1, pool, tiny GEMM
//
// R14 -> R15: gather2 invariant 52-59us across {FETCH 9.6..83MB, VALU 14..52%}
// -> suspect memory-level-parallelism floor (4 dependent row-loads in flight).
// Test: eighth-wave records -- lane q=lane>>3 owns record p+q, fl=lane&7 holds
// 8 features (uint4, row = 8 lanes x 16B). Unroll x4 = 32 rows in flight/wave
// (2x R14). Everything else identical to R14 (unpinned, k_expand stream,
// single accumulator + rare flush, 1024 blocks).
//
// DTYPE-ADAPTIVE: k_detect probes raw bits: flags[0]=bf16?, flags[1]=int64?

typedef __hip_bfloat16 bf16;
#define NGRAPH 128
#define NSLICE 8
#define TILE_C 16384
#define TILE_S 4096
#define SCAP   12288 // k_sort LDS stage capacity (mean 4096+256, >60 sigma)

__device__ __forceinline__ float b2f(bf16 v) { return __bfloat162float(v); }
__device__ __forceinline__ float fld(const void* p, long long i, int isbf) {
    return isbf ? b2f(((const bf16*)p)[i]) : ((const float*)p)[i];
}
__device__ __forceinline__ int ild(const void* p, long long i, int is64) {
    return is64 ? (int)((const long long*)p)[i] : ((const int*)p)[i];
}

// ---- dtype probe (parallel) ---------------------------------------------
__global__ void k_detect(const void* x, const void* ei, int* flags) {
    __shared__ int c[2];
    int l = threadIdx.x;  // 64
    if (l == 0) { c[0] = 0; c[1] = 0; }
    __syncthreads();
    const unsigned short* u = (const unsigned short*)x;
    int e1 = (u[4 * l] >> 7) & 0xFF;
    int e2 = (u[4 * l + 2] >> 7) & 0xFF;
    int good = ((e1 >= 90 && e1 <= 135) ? 1 : 0) + ((e2 >= 90 && e2 <= 135) ? 1 : 0);
    atomicAdd(&c[0], good);
    const int* w = (const int*)ei;
    if (w[2 * l + 1] == 0) atomicAdd(&c[1], 1);
    __syncthreads();
    if (l == 0) {
        flags[0] = (c[0] >= 96) ? 1 : 0;   // bf16 mode (128 samples)
        flags[1] = (c[1] >= 56) ? 1 : 0;   // int64 mode (64 samples)
    }
}

// ---- bucket histogram of dst>>8 ----------------------------------------
__global__ void k_count(const void* __restrict__ ei, int* __restrict__ cnt,
                        int E, int NB, const int* __restrict__ flags) {
    __shared__ int h[512];
    for (int b = threadIdx.x; b < NB; b += 256) h[b] = 0;
    __syncthreads();
    int is64 = flags[1];
    long long base = (long long)blockIdx.x * TILE_C;
    int lim = (int)min((long long)TILE_C, (long long)E - base);
    for (int k = threadIdx.x; k < lim; k += 256) {
        int d = ild(ei, (long long)E + base + k, is64);
        atomicAdd(&h[d >> 8], 1);
    }
    __syncthreads();
    for (int b = threadIdx.x; b < NB; b += 256)
        if (h[b]) atomicAdd(&cnt[b], h[b]);
}

// ---- bucket offsets (parallel scan, NB<=512) ----------------------------
__global__ void k_bscan(const int* __restrict__ cnt, int* __restrict__ bktoff2,
                        int* __restrict__ bktoff, int* __restrict__ gcur,
                        int N, int NB) {
    __shared__ int sa[512], sb[512];
    int i = threadIdx.x;
    int va = (i < NB) ? cnt[i] : 0;
    int nloc = (i < NB) ? min(256, N - (i << 8)) : 0;
    int vb = va + nloc;
    sa[i] = va; sb[i] = vb;
    __syncthreads();
    for (int d = 1; d < 512; d <<= 1) {
        int ta = (i >= d) ? sa[i - d] : 0;
        int tb = (i >= d) ? sb[i - d] : 0;
        __syncthreads();
        sa[i] += ta; sb[i] += tb;
        __syncthreads();
    }
    if (i < NB) {
        bktoff2[i] = sa[i] - va;
        bktoff[i] = sb[i] - vb;
        gcur[i] = sa[i] - va;
    }
    if (i == NB - 1) { bktoff2[NB] = sa[i]; bktoff[NB] = sb[i]; }
}

// ---- multisplit by dst bucket -------------------------------------------
__global__ void k_split(const void* __restrict__ ei, int2* __restrict__ edges2,
                        int* __restrict__ gcur, int E, int NB,
                        const int* __restrict__ flags) {
    __shared__ int hist[512], scan_[512], gbase[512], lcur[512];
    __shared__ int2 stage[TILE_S];
    int is64 = flags[1];
    long long base = (long long)blockIdx.x * TILE_S;
    int lim = (int)min((long long)TILE_S, (long long)E - base);
    for (int b = threadIdx.x; b < NB; b += 256) hist[b] = 0;
    __syncthreads();
    for (int k = threadIdx.x; k < lim; k += 256) {
        int d = ild(ei, (long long)E + base + k, is64);
        atomicAdd(&hist[d >> 8], 1);
    }
    __syncthreads();
    if (threadIdx.x == 0) {
        int a = 0;
        for (int i = 0; i < NB; ++i) { scan_[i] = a; a += hist[i]; }
    }
    __syncthreads();
    for (int b = threadIdx.x; b < NB; b += 256) {
        lcur[b] = scan_[b];
        gbase[b] = hist[b] ? atomicAdd(&gcur[b], hist[b]) : 0;
    }
    __syncthreads();
    for (int k = threadIdx.x; k < lim; k += 256) {
        int s = ild(ei, base + k, is64);
        int d = ild(ei, (long long)E + base + k, is64);
        int p = atomicAdd(&lcur[d >> 8], 1);
        stage[p] = make_int2(d, s);
    }
    __syncthreads();
    for (int t = threadIdx.x; t < lim; t += 256) {
        int2 r = stage[t];
        int b = r.x >> 8;
        edges2[gbase[b] + (t - scan_[b])] = r;
    }
}

// ---- per-bucket counting sort + fused node pass -------------------------
// meta = src | g<<17 | min(deg,255)<<24; slot 0 of each row = self record.
__global__ void k_sort(const int2* __restrict__ edges2, const void* __restrict__ batch,
                       const void* __restrict__ x, const int* __restrict__ cnt,
                       const int* __restrict__ bktoff2, const int* __restrict__ bktoff,
                       unsigned* __restrict__ meta, int* __restrict__ row_ptr,
                       float* __restrict__ dinv, float4* __restrict__ xs,
                       int* __restrict__ start, int N, int Etot,
                       const int* __restrict__ flags) {
    __shared__ int hist[256], loff[257], lcur[256], sc[256];
    __shared__ unsigned gdeg[256];
    __shared__ unsigned stage[SCAP];
    int b = blockIdx.x;
    int node0 = b << 8;
    int nloc = min(256, N - node0);
    int is64 = flags[1], isbf = flags[0];
    int i = threadIdx.x;
    if (i < nloc) hist[i] = 0;
    __syncthreads();
    int rbase = bktoff2[b], rcnt = cnt[b];
    for (int t = i; t < rcnt; t += 256) {
        int2 r = edges2[rbase + t];
        atomicAdd(&hist[r.x - node0], 1);
    }
    __syncthreads();
    int v = (i < nloc) ? hist[i] + 1 : 0;
    sc[i] = v;
    __syncthreads();
    for (int d = 1; d < 256; d <<= 1) {
        int t = (i >= d) ? sc[i - d] : 0;
        __syncthreads();
        sc[i] += t;
        __syncthreads();
    }
    if (i < nloc) loff[i] = sc[i] - v;
    if (i == nloc - 1) loff[nloc] = sc[i];
    __syncthreads();
    int mbase = bktoff[b];
    if (i < nloc) {
        int node = node0 + i;
        int dg = hist[i];
        float di = rsqrtf((float)(dg + 1));
        dinv[node] = di;
        row_ptr[node] = mbase + loff[i];
        int g = ild(batch, node, is64);
        int gp = (node == 0) ? -1 : ild(batch, node - 1, is64);
        for (int q = gp + 1; q <= g; ++q) start[q] = node;
        if (node == N - 1)
            for (int q = g + 1; q <= NGRAPH; ++q) start[q] = N;
        xs[node] = make_float4(di * fld(x, 3LL * node, isbf),
                               di * fld(x, 3LL * node + 1, isbf),
                               di * fld(x, 3LL * node + 2, isbf), 0.0f);
        unsigned gd = ((unsigned)g << 17) | ((unsigned)min(dg, 255) << 24);
        gdeg[i] = gd;
        lcur[i] = loff[i] + 1;                 // slot 0 = self record
        stage[loff[i]] = (unsigned)node | gd;
    }
    __syncthreads();
    for (int t = i; t < rcnt; t += 256) {
        int2 r = edges2[rbase + t];
        int dl = r.x - node0;
        int p = atomicAdd(&lcur[dl], 1);
        if (p < SCAP) stage[p] = (unsigned)r.y | gdeg[dl];
    }
    __syncthreads();
    int total = loff[nloc];
    for (int t = i; t < total; t += 256) meta[mbase + t] = stage[t];
    if (b == 0 && i == 0) row_ptr[N] = Etot;
}

// ---- layer 1 fused: CSR gather + tiny GEMM + relu -> hs1 ----------------
__global__ void k_l1(const float4* __restrict__ xs, const float* __restrict__ dinv,
                     const int* __restrict__ row_ptr, const unsigned* __restrict__ meta,
                     const void* __restrict__ W1, const void* __restrict__ b1,
                     bf16* __restrict__ hs1, int N, const int* __restrict__ flags) {
    __shared__ float w[256];        // [0..191]=W1 (3x64 row-major), [192..255]=b1
    __shared__ float ag[256][4];
    int isbf = flags[0];
    if (threadIdx.x < 192) w[threadIdx.x] = fld(W1, threadIdx.x, isbf);
    if (threadIdx.x < 64) w[192 + threadIdx.x] = fld(b1, threadIdx.x, isbf);
    int node0 = blockIdx.x << 8;
    int nloc = min(256, N - node0);
    int i = threadIdx.x;
    if (i < nloc) {
        int node = node0 + i;
        float ax = 0.f, ay = 0.f, az = 0.f;
        int p1 = row_ptr[node + 1];
        for (int p = row_ptr[node]; p < p1; ++p) {
            float4 vv = xs[meta[p] & 0x1FFFFu];
            ax += vv.x; ay += vv.y; az += vv.z;
        }
        float di = dinv[node];
        ag[i][0] = di * ax; ag[i][1] = di * ay; ag[i][2] = di * az;
        ag[i][3] = di;
    }
    __syncthreads();
    for (int t = threadIdx.x; t < (nloc << 6); t += 256) {
        int ii = t >> 6, j = t & 63;
        float acc = ag[ii][0] * w[j] + ag[ii][1] * w[64 + j] + ag[ii][2] * w[128 + j]
                  + w[192 + j];
        hs1[(size_t)(node0 + ii) * 64 + j] = __float2bfloat16(ag[ii][3] * fmaxf(acc, 0.0f));
    }
}

// ---- streaming expand: meta -> {src|g<<17, w=rsqrt(deg+1)} (meta order) --
__global__ void k_expand(const unsigned* __restrict__ meta, int2* __restrict__ rec2,
                         int Etot) {
    int i = blockIdx.x * 256 + threadIdx.x;
    if (i >= Etot) return;
    unsigned m = meta[i];
    rec2[i] = make_int2((int)(m & 0x00FFFFFFu),
                        __float_as_int(rsqrtf((float)((m >> 24) & 0xFFu) + 1.0f)));
}

// ---- layer 2 + pool: eighth-wave records, 32 rows in flight -------------
// lane q=lane>>3 -> record p+q; fl=lane&7 -> features 8fl..8fl+7 (uint4).
// 8 records per issue step, 32 in flight (unroll x4). g monotone per chunk.
__global__ void k_gather2(const uint4* __restrict__ hs1v, const int2* __restrict__ rec2,
                          float* __restrict__ P, int Etot, int chunk) {
    int wid = blockIdx.x * (blockDim.x >> 6) + (threadIdx.x >> 6);
    int lane = threadIdx.x & 63;
    int q = lane >> 3, fl = lane & 7;
    long long base = (long long)wid * chunk;
    if (base >= Etot) return;
    long long end = base + chunk;
    if (end > Etot) end = Etot;
    float a0 = 0.f, a1 = 0.f, a2 = 0.f, a3 = 0.f;
    float a4 = 0.f, a5 = 0.f, a6 = 0.f, a7 = 0.f;
    int gcur = -1;
    float* Pw = P + (size_t)(wid & (NSLICE - 1)) * (NGRAPH * 64);
#define FLUSH                                                                   \
    {                                                                           \
        atomicAdd(&Pw[gcur * 64 + 8 * fl + 0], a0);                             \
        atomicAdd(&Pw[gcur * 64 + 8 * fl + 1], a1);                             \
        atomicAdd(&Pw[gcur * 64 + 8 * fl + 2], a2);                             \
        atomicAdd(&Pw[gcur * 64 + 8 * fl + 3], a3);                             \
        atomicAdd(&Pw[gcur * 64 + 8 * fl + 4], a4);                             \
        atomicAdd(&Pw[gcur * 64 + 8 * fl + 5], a5);                             \
        atomicAdd(&Pw[gcur * 64 + 8 * fl + 6], a6);                             \
        atomicAdd(&Pw[gcur * 64 + 8 * fl + 7], a7);                             \
    }
#define STEP(m, h)                                                              \
    {                                                                           \
        int g = (int)((unsigned)m.x >> 17);                                     \
        if (__builtin_expect(g != gcur, 0)) {                                   \
            if (gcur >= 0) FLUSH;                                               \
            a0 = a1 = a2 = a3 = a4 = a5 = a6 = a7 = 0.f;                        \
            gcur = g;                                                           \
        }                                                                       \
        float w = __int_as_float(m.y);                                          \
        a0 += w * __uint_as_float(h.x << 16);                                   \
        a1 += w * __uint_as_float(h.x & 0xFFFF0000u);                           \
        a2 += w * __uint_as_float(h.y << 16);                                   \
        a3 += w * __uint_as_float(h.y & 0xFFFF0000u);                           \
        a4 += w * __uint_as_float(h.z << 16);                                   \
        a5 += w * __uint_as_float(h.z & 0xFFFF0000u);                           \
        a6 += w * __uint_as_float(h.w << 16);                                   \
        a7 += w * __uint_as_float(h.w & 0xFFFF0000u);                           \
    }
    long long p = base;
    for (; p + 31 < end; p += 32) {
        int2 m0 = rec2[p + q];
        int2 m1 = rec2[p + 8 + q];
        int2 m2 = rec2[p + 16 + q];
        int2 m3 = rec2[p + 24 + q];
        uint4 h0 = hs1v[(size_t)(m0.x & 0x1FFFF) * 8 + fl];
        uint4 h1 = hs1v[(size_t)(m1.x & 0x1FFFF) * 8 + fl];
        uint4 h2 = hs1v[(size_t)(m2.x & 0x1FFFF) * 8 + fl];
        uint4 h3 = hs1v[(size_t)(m3.x & 0x1FFFF) * 8 + fl];
        STEP(m0, h0) STEP(m1, h1) STEP(m2, h2) STEP(m3, h3)
    }
    for (; p < end; p += 8) {
        long long idx = p + q;
        if (idx < end) {
            int2 m = rec2[idx];
            uint4 h = hs1v[(size_t)(m.x & 0x1FFFF) * 8 + fl];
            STEP(m, h)
        }
    }
    if (gcur >= 0) FLUSH;
#undef STEP
#undef FLUSH
}

// out[g][j] = (sum_slices P[g]/count_g) . W2[:,j] + b2[j]  (0 if empty graph)
__global__ void k_out(const float* __restrict__ P, const int* __restrict__ start,
                      const void* __restrict__ W2, const void* __restrict__ b2v,
                      void* __restrict__ out, const int* __restrict__ flags) {
    __shared__ float pm[64];
    int g = blockIdx.x, j = threadIdx.x;
    int isbf = flags[0];
    int c = start[g + 1] - start[g];
    if (j < 64) {
        float v = 0.f;
        for (int s = 0; s < NSLICE; ++s) v += P[(size_t)s * NGRAPH * 64 + g * 64 + j];
        pm[j] = (c > 0) ? v / (float)c : 0.0f;
    }
    __syncthreads();
    float acc = 0.0f;
    if (c > 0) {
        acc = fld(b2v, j, isbf);
        for (int k = 0; k < 64; ++k) acc += pm[k] * fld(W2, k * 128 + j, isbf);
    }
    if (isbf) ((bf16*)out)[g * 128 + j] = __float2bfloat16(acc);
    else      ((float*)out)[g * 128 + j] = acc;
}

extern "C" void kernel_launch(void* const* d_in, const int* in_sizes, int n_in,
                              void* d_out, int out_size, void* d_ws, size_t ws_size,
                              hipStream_t stream) {
    const void* x    = d_in[0];
    const void* ei   = d_in[1];   // edge_index [2,E] flat: src row then dst row
    const void* batch= d_in[2];
    const void* W1   = d_in[3];
    const void* b1   = d_in[4];
    const void* W2   = d_in[5];
    const void* b2   = d_in[6];

    const int N = in_sizes[0] / 3;
    const int E = in_sizes[1] / 2;
    const int Etot = E + N;
    const int NB = (N + 255) / 256;          // dst buckets (391)

    // ---- workspace layout (512B aligned), total ~51 MB ----
    char* ws = (char*)d_ws;
    size_t off = 0;
    auto alloc = [&](size_t bytes) {
        size_t o = off;
        off = (off + bytes + 511) & ~(size_t)511;
        return o;
    };
    int* flags    = (int*)(ws + alloc(64 * 4));
    int* cnt      = (int*)(ws + alloc((size_t)NB * 4));
    int* bktoff2  = (int*)(ws + alloc((size_t)(NB + 1) * 4));
    int* bktoff   = (int*)(ws + alloc((size_t)(NB + 1) * 4));
    int* gcur     = (int*)(ws + alloc((size_t)NB * 4));
    int* start    = (int*)(ws + alloc((size_t)(NGRAPH + 1) * 4));
    int* row_ptr  = (int*)(ws + alloc((size_t)(N + 1) * 4));
    float* dinv   = (float*)(ws + alloc((size_t)N * 4));
    int2* edges2  = (int2*)(ws + alloc((size_t)E * 8));
    unsigned* meta= (unsigned*)(ws + alloc((size_t)Etot * 4));
    int2* rec2    = (int2*)(ws + alloc((size_t)Etot * 8));
    float4* xs    = (float4*)(ws + alloc((size_t)N * 16));
    bf16* hs1     = (bf16*)(ws + alloc((size_t)N * 64 * 2));
    float* P      = (float*)(ws + alloc((size_t)NSLICE * NGRAPH * 64 * 4));
    (void)ws_size;

    (void)hipMemsetAsync(cnt, 0, (size_t)NB * 4, stream);
    (void)hipMemsetAsync(P, 0, (size_t)NSLICE * NGRAPH * 64 * 4, stream);

    const int cb = (E + TILE_C - 1) / TILE_C;       // 98
    const int sb = (E + TILE_S - 1) / TILE_S;       // 391
    const int xb = (Etot + 255) / 256;              // 6641

    // gather2: 1024 blocks -> 4096 waves, 32 records in flight per wave
    const int g2blocks = 1024;
    const int g2waves = g2blocks * 4;
    const int chunk = (Etot + g2waves - 1) / g2waves;

    k_detect<<<1, 64, 0, stream>>>(x, ei, flags);
    k_count<<<cb, 256, 0, stream>>>(ei, cnt, E, NB, flags);
    k_bscan<<<1, 512, 0, stream>>>(cnt, bktoff2, bktoff, gcur, N, NB);
    k_split<<<sb, 256, 0, stream>>>(ei, edges2, gcur, E, NB, flags);
    k_sort<<<NB, 256, 0, stream>>>(edges2, batch, x, cnt, bktoff2, bktoff, meta,
                                   row_ptr, dinv, xs, start, N, Etot, flags);
    k_l1<<<NB, 256, 0, stream>>>(xs, dinv, row_ptr, meta, W1, b1, hs1, N, flags);
    k_expand<<<xb, 256, 0, stream>>>(meta, rec2, Etot);
    k_gather2<<<g2blocks, 256, 0, stream>>>((const uint4*)hs1, rec2, P, Etot, chunk);
    k_out<<<NGRAPH, 128, 0, stream>>>(P, start, W2, b2, d_out, flags);
}

// Round 16
// 229.239 us; speedup vs baseline: 1.4733x; 1.4733x over previous
//
#include <hip/hip_runtime.h>
#include <hip/hip_bf16.h>

// 2-layer GCN + mean pool. N=100000, E=1600000, G=128. dims 3 -> 64 -> 128.
//   h1  = relu( (A_hat x) @ W1 + b1 )        -- aggregate 3-dim x, then tiny GEMM
//   out = (mean_g (A_hat h1)) @ W2 + b2      -- aggregate 64-dim h1, pool, tiny GEMM
//
// R15 -> R16: eighth-wave gather2 REVERTED (169us: 8-way same-address flush
// atomics + P-line ping-pong across XCDs, WRITE 67MB). Back to R14's
// quarter-wave loop (56us floor) with P slice = blockIdx&7 (slice lines stay
// on one XCD -> no atomic line bounce). Build pipeline slimmed:
//   * k_expand + meta KILLED: k_sort writes rec2={src|g<<17, w=rsqrt(deg+1)}
//     directly (coalesced); k_l1 reads rec2.x. -1 kernel, -14MB traffic.
//   * k_split's thread-0 serial 391-entry scan -> parallel (2/thread + HS).
//
// DTYPE-ADAPTIVE: k_detect probes raw bits: flags[0]=bf16?, flags[1]=int64?

typedef __hip_bfloat16 bf16;
#define NGRAPH 128
#define NSLICE 8
#define TILE_C 16384
#define TILE_S 4096
#define SCAP   12288 // k_sort LDS stage capacity (mean 4096+256, >60 sigma)

__device__ __forceinline__ float b2f(bf16 v) { return __bfloat162float(v); }
__device__ __forceinline__ float fld(const void* p, long long i, int isbf) {
    return isbf ? b2f(((const bf16*)p)[i]) : ((const float*)p)[i];
}
__device__ __forceinline__ int ild(const void* p, long long i, int is64) {
    return is64 ? (int)((const long long*)p)[i] : ((const int*)p)[i];
}

// ---- dtype probe (parallel) ---------------------------------------------
__global__ void k_detect(const void* x, const void* ei, int* flags) {
    __shared__ int c[2];
    int l = threadIdx.x;  // 64
    if (l == 0) { c[0] = 0; c[1] = 0; }
    __syncthreads();
    const unsigned short* u = (const unsigned short*)x;
    int e1 = (u[4 * l] >> 7) & 0xFF;
    int e2 = (u[4 * l + 2] >> 7) & 0xFF;
    int good = ((e1 >= 90 && e1 <= 135) ? 1 : 0) + ((e2 >= 90 && e2 <= 135) ? 1 : 0);
    atomicAdd(&c[0], good);
    const int* w = (const int*)ei;
    if (w[2 * l + 1] == 0) atomicAdd(&c[1], 1);
    __syncthreads();
    if (l == 0) {
        flags[0] = (c[0] >= 96) ? 1 : 0;   // bf16 mode (128 samples)
        flags[1] = (c[1] >= 56) ? 1 : 0;   // int64 mode (64 samples)
    }
}

// ---- bucket histogram of dst>>8 ----------------------------------------
__global__ void k_count(const void* __restrict__ ei, int* __restrict__ cnt,
                        int E, int NB, const int* __restrict__ flags) {
    __shared__ int h[512];
    for (int b = threadIdx.x; b < NB; b += 256) h[b] = 0;
    __syncthreads();
    int is64 = flags[1];
    long long base = (long long)blockIdx.x * TILE_C;
    int lim = (int)min((long long)TILE_C, (long long)E - base);
    for (int k = threadIdx.x; k < lim; k += 256) {
        int d = ild(ei, (long long)E + base + k, is64);
        atomicAdd(&h[d >> 8], 1);
    }
    __syncthreads();
    for (int b = threadIdx.x; b < NB; b += 256)
        if (h[b]) atomicAdd(&cnt[b], h[b]);
}

// ---- bucket offsets (parallel scan, NB<=512) ----------------------------
__global__ void k_bscan(const int* __restrict__ cnt, int* __restrict__ bktoff2,
                        int* __restrict__ bktoff, int* __restrict__ gcur,
                        int N, int NB) {
    __shared__ int sa[512], sb[512];
    int i = threadIdx.x;
    int va = (i < NB) ? cnt[i] : 0;
    int nloc = (i < NB) ? min(256, N - (i << 8)) : 0;
    int vb = va + nloc;
    sa[i] = va; sb[i] = vb;
    __syncthreads();
    for (int d = 1; d < 512; d <<= 1) {
        int ta = (i >= d) ? sa[i - d] : 0;
        int tb = (i >= d) ? sb[i - d] : 0;
        __syncthreads();
        sa[i] += ta; sb[i] += tb;
        __syncthreads();
    }
    if (i < NB) {
        bktoff2[i] = sa[i] - va;
        bktoff[i] = sb[i] - vb;
        gcur[i] = sa[i] - va;
    }
    if (i == NB - 1) { bktoff2[NB] = sa[i]; bktoff[NB] = sb[i]; }
}

// ---- multisplit by dst bucket (parallel in-block scan) ------------------
__global__ void k_split(const void* __restrict__ ei, int2* __restrict__ edges2,
                        int* __restrict__ gcur, int E, int NB,
                        const int* __restrict__ flags) {
    __shared__ int hist[512], scan_[512], gbase[512], lcur[512], sc[256];
    __shared__ int2 stage[TILE_S];
    int is64 = flags[1];
    long long base = (long long)blockIdx.x * TILE_S;
    int lim = (int)min((long long)TILE_S, (long long)E - base);
    int i = threadIdx.x;
    for (int b = i; b < NB; b += 256) hist[b] = 0;
    __syncthreads();
    for (int k = i; k < lim; k += 256) {
        int d = ild(ei, (long long)E + base + k, is64);
        atomicAdd(&hist[d >> 8], 1);
    }
    __syncthreads();
    // parallel exclusive scan of hist[0..NB): 2 entries/thread + HS over pairs
    int v0 = (2 * i < NB) ? hist[2 * i] : 0;
    int v1 = (2 * i + 1 < NB) ? hist[2 * i + 1] : 0;
    int ps = v0 + v1;
    sc[i] = ps;
    __syncthreads();
    for (int d = 1; d < 256; d <<= 1) {
        int t = (i >= d) ? sc[i - d] : 0;
        __syncthreads();
        sc[i] += t;
        __syncthreads();
    }
    int excl = sc[i] - ps;
    if (2 * i < NB) scan_[2 * i] = excl;
    if (2 * i + 1 < NB) scan_[2 * i + 1] = excl + v0;
    __syncthreads();
    for (int b = i; b < NB; b += 256) {
        lcur[b] = scan_[b];
        gbase[b] = hist[b] ? atomicAdd(&gcur[b], hist[b]) : 0;
    }
    __syncthreads();
    for (int k = i; k < lim; k += 256) {
        int s = ild(ei, base + k, is64);
        int d = ild(ei, (long long)E + base + k, is64);
        int p = atomicAdd(&lcur[d >> 8], 1);
        stage[p] = make_int2(d, s);
    }
    __syncthreads();
    for (int t = i; t < lim; t += 256) {
        int2 r = stage[t];
        int b = r.x >> 8;
        edges2[gbase[b] + (t - scan_[b])] = r;
    }
}

// ---- per-bucket counting sort + fused node pass -------------------------
// rec2 = { src | g<<17 , w = rsqrt(deg_dst+1) }; slot 0 of each row = self.
__global__ void k_sort(const int2* __restrict__ edges2, const void* __restrict__ batch,
                       const void* __restrict__ x, const int* __restrict__ cnt,
                       const int* __restrict__ bktoff2, const int* __restrict__ bktoff,
                       int2* __restrict__ rec2, int* __restrict__ row_ptr,
                       float* __restrict__ dinv, float4* __restrict__ xs,
                       int* __restrict__ start, int N, int Etot,
                       const int* __restrict__ flags) {
    __shared__ int hist[256], loff[257], lcur[256], sc[256];
    __shared__ unsigned gdeg[256];
    __shared__ unsigned stage[SCAP];
    int b = blockIdx.x;
    int node0 = b << 8;
    int nloc = min(256, N - node0);
    int is64 = flags[1], isbf = flags[0];
    int i = threadIdx.x;
    if (i < nloc) hist[i] = 0;
    __syncthreads();
    int rbase = bktoff2[b], rcnt = cnt[b];
    for (int t = i; t < rcnt; t += 256) {
        int2 r = edges2[rbase + t];
        atomicAdd(&hist[r.x - node0], 1);
    }
    __syncthreads();
    int v = (i < nloc) ? hist[i] + 1 : 0;
    sc[i] = v;
    __syncthreads();
    for (int d = 1; d < 256; d <<= 1) {
        int t = (i >= d) ? sc[i - d] : 0;
        __syncthreads();
        sc[i] += t;
        __syncthreads();
    }
    if (i < nloc) loff[i] = sc[i] - v;
    if (i == nloc - 1) loff[nloc] = sc[i];
    __syncthreads();
    int mbase = bktoff[b];
    if (i < nloc) {
        int node = node0 + i;
        int dg = hist[i];
        float di = rsqrtf((float)(dg + 1));
        dinv[node] = di;
        row_ptr[node] = mbase + loff[i];
        int g = ild(batch, node, is64);
        int gp = (node == 0) ? -1 : ild(batch, node - 1, is64);
        for (int q = gp + 1; q <= g; ++q) start[q] = node;
        if (node == N - 1)
            for (int q = g + 1; q <= NGRAPH; ++q) start[q] = N;
        xs[node] = make_float4(di * fld(x, 3LL * node, isbf),
                               di * fld(x, 3LL * node + 1, isbf),
                               di * fld(x, 3LL * node + 2, isbf), 0.0f);
        unsigned gd = ((unsigned)g << 17) | ((unsigned)min(dg, 255) << 24);
        gdeg[i] = gd;
        lcur[i] = loff[i] + 1;                 // slot 0 = self record
        stage[loff[i]] = (unsigned)node | gd;
    }
    __syncthreads();
    for (int t = i; t < rcnt; t += 256) {
        int2 r = edges2[rbase + t];
        int dl = r.x - node0;
        int p = atomicAdd(&lcur[dl], 1);
        if (p < SCAP) stage[p] = (unsigned)r.y | gdeg[dl];
    }
    __syncthreads();
    int total = loff[nloc];
    for (int t = i; t < total; t += 256) {
        unsigned m = stage[t];
        rec2[mbase + t] = make_int2((int)(m & 0x00FFFFFFu),
            __float_as_int(rsqrtf((float)((m >> 24) & 0xFFu) + 1.0f)));
    }
    if (b == 0 && i == 0) row_ptr[N] = Etot;
}

// ---- layer 1 fused: CSR gather + tiny GEMM + relu -> hs1 ----------------
__global__ void k_l1(const float4* __restrict__ xs, const float* __restrict__ dinv,
                     const int* __restrict__ row_ptr, const int2* __restrict__ rec2,
                     const void* __restrict__ W1, const void* __restrict__ b1,
                     bf16* __restrict__ hs1, int N, const int* __restrict__ flags) {
    __shared__ float w[256];        // [0..191]=W1 (3x64 row-major), [192..255]=b1
    __shared__ float ag[256][4];
    int isbf = flags[0];
    if (threadIdx.x < 192) w[threadIdx.x] = fld(W1, threadIdx.x, isbf);
    if (threadIdx.x < 64) w[192 + threadIdx.x] = fld(b1, threadIdx.x, isbf);
    int node0 = blockIdx.x << 8;
    int nloc = min(256, N - node0);
    int i = threadIdx.x;
    if (i < nloc) {
        int node = node0 + i;
        float ax = 0.f, ay = 0.f, az = 0.f;
        int p1 = row_ptr[node + 1];
        for (int p = row_ptr[node]; p < p1; ++p) {
            float4 vv = xs[rec2[p].x & 0x1FFFF];
            ax += vv.x; ay += vv.y; az += vv.z;
        }
        float di = dinv[node];
        ag[i][0] = di * ax; ag[i][1] = di * ay; ag[i][2] = di * az;
        ag[i][3] = di;
    }
    __syncthreads();
    for (int t = threadIdx.x; t < (nloc << 6); t += 256) {
        int ii = t >> 6, j = t & 63;
        float acc = ag[ii][0] * w[j] + ag[ii][1] * w[64 + j] + ag[ii][2] * w[128 + j]
                  + w[192 + j];
        hs1[(size_t)(node0 + ii) * 64 + j] = __float2bfloat16(ag[ii][3] * fmaxf(acc, 0.0f));
    }
}

// ---- layer 2 + pool: quarter-wave records (R14 floor config) ------------
// lane q=lane>>4 -> record p+q; fl=lane&15 -> features 4fl..4fl+3 (uint2).
// P slice = blockIdx&7: slice lines stay on one XCD (no atomic line bounce).
__global__ void k_gather2(const uint2* __restrict__ hs1v, const int2* __restrict__ rec2,
                          float* __restrict__ P, int Etot, int chunk) {
    int wid = blockIdx.x * (blockDim.x >> 6) + (threadIdx.x >> 6);
    int lane = threadIdx.x & 63;
    int q = lane >> 4, fl = lane & 15;
    long long base = (long long)wid * chunk;
    if (base >= Etot) return;
    long long end = base + chunk;
    if (end > Etot) end = Etot;
    float a0 = 0.f, a1 = 0.f, a2 = 0.f, a3 = 0.f;
    int gcur = -1;
    float* Pw = P + (size_t)(blockIdx.x & (NSLICE - 1)) * (NGRAPH * 64);
#define STEP(m, h)                                                              \
    {                                                                           \
        int g = (int)((unsigned)m.x >> 17);                                     \
        if (__builtin_expect(g != gcur, 0)) {                                   \
            if (gcur >= 0) {                                                    \
                atomicAdd(&Pw[gcur * 64 + 4 * fl + 0], a0);                     \
                atomicAdd(&Pw[gcur * 64 + 4 * fl + 1], a1);                     \
                atomicAdd(&Pw[gcur * 64 + 4 * fl + 2], a2);                     \
                atomicAdd(&Pw[gcur * 64 + 4 * fl + 3], a3);                     \
            }                                                                   \
            a0 = a1 = a2 = a3 = 0.f; gcur = g;                                  \
        }                                                                       \
        float w = __int_as_float(m.y);                                          \
        a0 += w * __uint_as_float(h.x << 16);                                   \
        a1 += w * __uint_as_float(h.x & 0xFFFF0000u);                           \
        a2 += w * __uint_as_float(h.y << 16);                                   \
        a3 += w * __uint_as_float(h.y & 0xFFFF0000u);                           \
    }
    long long p = base;
    for (; p + 15 < end; p += 16) {
        int2 m0 = rec2[p + q];
        int2 m1 = rec2[p + 4 + q];
        int2 m2 = rec2[p + 8 + q];
        int2 m3 = rec2[p + 12 + q];
        uint2 h0 = hs1v[(size_t)(m0.x & 0x1FFFF) * 16 + fl];
        uint2 h1 = hs1v[(size_t)(m1.x & 0x1FFFF) * 16 + fl];
        uint2 h2 = hs1v[(size_t)(m2.x & 0x1FFFF) * 16 + fl];
        uint2 h3 = hs1v[(size_t)(m3.x & 0x1FFFF) * 16 + fl];
        STEP(m0, h0) STEP(m1, h1) STEP(m2, h2) STEP(m3, h3)
    }
    for (; p < end; p += 4) {
        long long idx = p + q;
        if (idx < end) {
            int2 m = rec2[idx];
            uint2 h = hs1v[(size_t)(m.x & 0x1FFFF) * 16 + fl];
            STEP(m, h)
        }
    }
#undef STEP
    if (gcur >= 0) {
        atomicAdd(&Pw[gcur * 64 + 4 * fl + 0], a0);
        atomicAdd(&Pw[gcur * 64 + 4 * fl + 1], a1);
        atomicAdd(&Pw[gcur * 64 + 4 * fl + 2], a2);
        atomicAdd(&Pw[gcur * 64 + 4 * fl + 3], a3);
    }
}

// out[g][j] = (sum_slices P[g]/count_g) . W2[:,j] + b2[j]  (0 if empty graph)
__global__ void k_out(const float* __restrict__ P, const int* __restrict__ start,
                      const void* __restrict__ W2, const void* __restrict__ b2v,
                      void* __restrict__ out, const int* __restrict__ flags) {
    __shared__ float pm[64];
    int g = blockIdx.x, j = threadIdx.x;
    int isbf = flags[0];
    int c = start[g + 1] - start[g];
    if (j < 64) {
        float v = 0.f;
        for (int s = 0; s < NSLICE; ++s) v += P[(size_t)s * NGRAPH * 64 + g * 64 + j];
        pm[j] = (c > 0) ? v / (float)c : 0.0f;
    }
    __syncthreads();
    float acc = 0.0f;
    if (c > 0) {
        acc = fld(b2v, j, isbf);
        for (int k = 0; k < 64; ++k) acc += pm[k] * fld(W2, k * 128 + j, isbf);
    }
    if (isbf) ((bf16*)out)[g * 128 + j] = __float2bfloat16(acc);
    else      ((float*)out)[g * 128 + j] = acc;
}

extern "C" void kernel_launch(void* const* d_in, const int* in_sizes, int n_in,
                              void* d_out, int out_size, void* d_ws, size_t ws_size,
                              hipStream_t stream) {
    const void* x    = d_in[0];
    const void* ei   = d_in[1];   // edge_index [2,E] flat: src row then dst row
    const void* batch= d_in[2];
    const void* W1   = d_in[3];
    const void* b1   = d_in[4];
    const void* W2   = d_in[5];
    const void* b2   = d_in[6];

    const int N = in_sizes[0] / 3;
    const int E = in_sizes[1] / 2;
    const int Etot = E + N;
    const int NB = (N + 255) / 256;          // dst buckets (391)

    // ---- workspace layout (512B aligned), total ~45 MB ----
    char* ws = (char*)d_ws;
    size_t off = 0;
    auto alloc = [&](size_t bytes) {
        size_t o = off;
        off = (off + bytes + 511) & ~(size_t)511;
        return o;
    };
    int* flags    = (int*)(ws + alloc(64 * 4));
    int* cnt      = (int*)(ws + alloc((size_t)NB * 4));
    int* bktoff2  = (int*)(ws + alloc((size_t)(NB + 1) * 4));
    int* bktoff   = (int*)(ws + alloc((size_t)(NB + 1) * 4));
    int* gcur     = (int*)(ws + alloc((size_t)NB * 4));
    int* start    = (int*)(ws + alloc((size_t)(NGRAPH + 1) * 4));
    int* row_ptr  = (int*)(ws + alloc((size_t)(N + 1) * 4));
    float* dinv   = (float*)(ws + alloc((size_t)N * 4));
    int2* edges2  = (int2*)(ws + alloc((size_t)E * 8));
    int2* rec2    = (int2*)(ws + alloc((size_t)Etot * 8));
    float4* xs    = (float4*)(ws + alloc((size_t)N * 16));
    bf16* hs1     = (bf16*)(ws + alloc((size_t)N * 64 * 2));
    float* P      = (float*)(ws + alloc((size_t)NSLICE * NGRAPH * 64 * 4));
    (void)ws_size;

    (void)hipMemsetAsync(cnt, 0, (size_t)NB * 4, stream);
    (void)hipMemsetAsync(P, 0, (size_t)NSLICE * NGRAPH * 64 * 4, stream);

    const int cb = (E + TILE_C - 1) / TILE_C;       // 98
    const int sb = (E + TILE_S - 1) / TILE_S;       // 391

    // gather2: 1024 blocks -> 4096 waves, 16 records in flight per wave
    const int g2blocks = 1024;
    const int g2waves = g2blocks * 4;
    const int chunk = (Etot + g2waves - 1) / g2waves;

    k_detect<<<1, 64, 0, stream>>>(x, ei, flags);
    k_count<<<cb, 256, 0, stream>>>(ei, cnt, E, NB, flags);
    k_bscan<<<1, 512, 0, stream>>>(cnt, bktoff2, bktoff, gcur, N, NB);
    k_split<<<sb, 256, 0, stream>>>(ei, edges2, gcur, E, NB, flags);
    k_sort<<<NB, 256, 0, stream>>>(edges2, batch, x, cnt, bktoff2, bktoff, rec2,
                                   row_ptr, dinv, xs, start, N, Etot, flags);
    k_l1<<<NB, 256, 0, stream>>>(xs, dinv, row_ptr, rec2, W1, b1, hs1, N, flags);
    k_gather2<<<g2blocks, 256, 0, stream>>>((const uint2*)hs1, rec2, P, Etot, chunk);
    k_out<<<NGRAPH, 128, 0, stream>>>(P, start, W2, b2, d_out, flags);
}